// Round 6
// baseline (269.762 us; speedup 1.0000x reference)
//
#include <hip/hip_runtime.h>
#include <hip/hip_bf16.h>

typedef short short8 __attribute__((ext_vector_type(8)));
typedef float f32x4 __attribute__((ext_vector_type(4)));
typedef float f32x16 __attribute__((ext_vector_type(16)));

#define MFMA16(a, b, c) __builtin_amdgcn_mfma_f32_16x16x32_bf16((a), (b), (c), 0, 0, 0)
#define MFMA32(a, b, c) __builtin_amdgcn_mfma_f32_32x32x16_bf16((a), (b), (c), 0, 0, 0)

// async global->LDS, 16B per lane; LDS dest = wave-uniform base + lane*16
#define GLOAD16(gp, lp)                                                    \
    __builtin_amdgcn_global_load_lds(                                      \
        (const __attribute__((address_space(1))) unsigned int*)(gp),       \
        (__attribute__((address_space(3))) unsigned int*)(lp), 16, 0, 0)

__device__ __forceinline__ unsigned short f2b(float x) {
    unsigned int u = __float_as_uint(x);
    unsigned int r = u + 0x7FFFu + ((u >> 16) & 1u);
    return (unsigned short)(r >> 16);
}

#if __has_builtin(__builtin_amdgcn_cvt_pk_bf16_f32)
__device__ __forceinline__ unsigned pack2(float a, float b) {
    auto v = __builtin_amdgcn_cvt_pk_bf16_f32(a, b);
    unsigned u;
    __builtin_memcpy(&u, &v, 4);
    return u;
}
#else
__device__ __forceinline__ unsigned pack2(float a, float b) {
    return (unsigned)f2b(a) | ((unsigned)f2b(b) << 16);
}
#endif

// ---------------------------------------------------------------- x -> bf16
__global__ __launch_bounds__(256) void cast4_kernel(const float* __restrict__ in,
                                                    unsigned short* __restrict__ out,
                                                    int n4) {
    int i = blockIdx.x * 256 + threadIdx.x;
    if (i < n4) {
        float4 v = ((const float4*)in)[i];
        ushort4 o;
        o.x = f2b(v.x); o.y = f2b(v.y); o.z = f2b(v.z); o.w = f2b(v.w);
        ((ushort4*)out)[i] = o;
    }
}

// ---------------------------------------------------------------- weights: f32 KxN -> bf16 NxK (LDS-tiled)
__global__ __launch_bounds__(256) void transpose_cast_f32(const float* __restrict__ in,
                                                          unsigned short* __restrict__ out,
                                                          int K, int N) {
    __shared__ unsigned short Ls[64 * 66];
    const int k0 = blockIdx.y * 64, n0 = blockIdx.x * 64;
    const int tid = threadIdx.x;
    const int krow = tid >> 4, nc4 = (tid & 15) * 4;
#pragma unroll
    for (int p = 0; p < 4; p++) {
        float4 v = *(const float4*)(in + (size_t)(k0 + krow + p * 16) * N + n0 + nc4);
        unsigned* d32 = (unsigned*)(Ls + (krow + p * 16) * 66 + nc4);
        d32[0] = pack2(v.x, v.y);
        d32[1] = pack2(v.z, v.w);
    }
    __syncthreads();
    const int n = tid >> 3, kc = (tid & 7) * 8;
#pragma unroll
    for (int p = 0; p < 2; p++) {
        int nn = n + p * 32;
        unsigned short w[8];
#pragma unroll
        for (int j = 0; j < 8; j++) w[j] = Ls[(kc + j) * 66 + nn];
        *(short8*)(out + (size_t)(n0 + nn) * K + k0 + kc) = *(short8*)w;
    }
}

// ---------------------------------------------------------------- Q/K GEMM
// 256x256 tile, BK=64, 8 waves (2Mx4N), double-buffered 128KB LDS, 4-phase
// counted-vmcnt(6) schedule. Grid 32x8 = 256 blocks = EXACTLY 1 round (no tail).
// MFMA operands SWAPPED (computes D^T): lane=output row, regs=4-consecutive-col
// runs -> packed 8B C-stores (32 uint2/thread vs 128 scalar ushort).
__global__ __launch_bounds__(512, 2) void gemm_qk(const unsigned short* __restrict__ A,
                                                  const unsigned short* __restrict__ Bt,
                                                  unsigned short* __restrict__ Qb,
                                                  unsigned short* __restrict__ Kb) {
    __shared__ __align__(16) unsigned short smem[65536]; // A[2][16384] | B[2][16384]

    const int tid  = threadIdx.x;
    const int wave = tid >> 6;
    const int lane = tid & 63;
    const int l32  = lane & 31;
    const int hi   = lane >> 5;
    const int wr   = wave >> 2;   // 0..1  (M)
    const int wc   = wave & 3;    // 0..3  (N)

    // XCD-aware bijective swizzle: 256 blocks, 256%8==0.
    const int bid = blockIdx.x;
    const int sid = (bid & 7) * 32 + (bid >> 3);
    const int bx  = sid & 7;      // 8 N-blocks
    const int by  = sid >> 3;     // 32 M-blocks
    const int m0 = by * 256;
    const int n0 = bx * 256;

    const int srow = tid >> 3;                              // 0..63
    const int cswz = (((tid & 7) ^ ((tid >> 3) & 7)) * 8);  // swizzled col (shorts)
    const unsigned short* gA = A  + (size_t)(m0 + srow) * 1024 + cswz;
    const unsigned short* gB = Bt + (size_t)(n0 + srow) * 1024 + cswz;

#define STAGE_A(buf, h, kt) do {                                              \
        const unsigned short* _g = gA + (size_t)((h) * 128) * 1024 + (kt) * 64; \
        unsigned short* _l = smem + (buf) * 16384 + (h) * 8192 + wave * 512;  \
        GLOAD16(_g, _l);                                                      \
        GLOAD16(_g + 65536, _l + 4096);                                       \
    } while (0)
#define STAGE_B(buf, h, kt) do {                                              \
        const unsigned short* _g = gB + (size_t)((h) * 128) * 1024 + (kt) * 64; \
        unsigned short* _l = smem + 32768 + (buf) * 16384 + (h) * 8192 + wave * 512; \
        GLOAD16(_g, _l);                                                      \
        GLOAD16(_g + 65536, _l + 4096);                                       \
    } while (0)

    const int sw7  = l32 & 7;
    const int aoff = (wr * 128 + l32) * 64;
    const int boff = (wc * 64 + l32) * 64;

    f32x16 acc[4][2] = {};

    STAGE_A(0, 0, 0); STAGE_A(0, 1, 0); STAGE_B(0, 0, 0); STAGE_B(0, 1, 0);
    STAGE_B(1, 0, 1); STAGE_B(1, 1, 1); STAGE_A(1, 0, 1);
    asm volatile("s_waitcnt vmcnt(6)" ::: "memory");
    __builtin_amdgcn_s_barrier();

#pragma unroll
    for (int t = 0; t < 16; ++t) {
        const int b = t & 1;
        const unsigned short* Ab = smem + b * 16384;
        const unsigned short* Bb = smem + 32768 + b * 16384;

        short8 afLo[2][4], afHi[2][4], bf0[4], bf1[4];

        // -------- phase 1: afLo + bf0 | stage A1(t+1) | q0
#pragma unroll
        for (int rf = 0; rf < 2; ++rf)
#pragma unroll
            for (int ks = 0; ks < 4; ++ks)
                afLo[rf][ks] = *(const short8*)(Ab + aoff + rf * 2048 + (((ks * 2 + hi) ^ sw7) * 8));
#pragma unroll
        for (int ks = 0; ks < 4; ++ks)
            bf0[ks] = *(const short8*)(Bb + boff + (((ks * 2 + hi) ^ sw7) * 8));
        if (t + 1 < 16) STAGE_A(b ^ 1, 1, t + 1);
        __builtin_amdgcn_s_barrier();
        asm volatile("s_waitcnt lgkmcnt(0)" ::: "memory");
        __builtin_amdgcn_s_setprio(1);
#pragma unroll
        for (int ks = 0; ks < 4; ++ks) {
            acc[0][0] = MFMA32(bf0[ks], afLo[0][ks], acc[0][0]);
            acc[1][0] = MFMA32(bf0[ks], afLo[1][ks], acc[1][0]);
        }
        __builtin_amdgcn_s_setprio(0);
        __builtin_amdgcn_s_barrier();

        // -------- phase 2: bf1 | q1
#pragma unroll
        for (int ks = 0; ks < 4; ++ks)
            bf1[ks] = *(const short8*)(Bb + boff + 2048 + (((ks * 2 + hi) ^ sw7) * 8));
        __builtin_amdgcn_s_barrier();
        asm volatile("s_waitcnt lgkmcnt(0)" ::: "memory");
        __builtin_amdgcn_s_setprio(1);
#pragma unroll
        for (int ks = 0; ks < 4; ++ks) {
            acc[0][1] = MFMA32(bf1[ks], afLo[0][ks], acc[0][1]);
            acc[1][1] = MFMA32(bf1[ks], afLo[1][ks], acc[1][1]);
        }
        __builtin_amdgcn_s_setprio(0);
        __builtin_amdgcn_s_barrier();

        // -------- phase 3: afHi | stage B0,B1(t+2) | q2
#pragma unroll
        for (int rf = 0; rf < 2; ++rf)
#pragma unroll
            for (int ks = 0; ks < 4; ++ks)
                afHi[rf][ks] = *(const short8*)(Ab + aoff + (2 + rf) * 2048 + (((ks * 2 + hi) ^ sw7) * 8));
        if (t + 2 < 16) { STAGE_B(b, 0, t + 2); STAGE_B(b, 1, t + 2); }
        __builtin_amdgcn_s_barrier();
        asm volatile("s_waitcnt lgkmcnt(0)" ::: "memory");
        __builtin_amdgcn_s_setprio(1);
#pragma unroll
        for (int ks = 0; ks < 4; ++ks) {
            acc[2][0] = MFMA32(bf0[ks], afHi[0][ks], acc[2][0]);
            acc[3][0] = MFMA32(bf0[ks], afHi[1][ks], acc[3][0]);
        }
        __builtin_amdgcn_s_setprio(0);
        __builtin_amdgcn_s_barrier();

        // -------- phase 4: stage A0(t+2) | counted vmcnt | q3
        if (t + 2 < 16) {
            STAGE_A(b, 0, t + 2);
            asm volatile("s_waitcnt vmcnt(6)" ::: "memory");
        } else {
            asm volatile("s_waitcnt vmcnt(0)" ::: "memory");
        }
        __builtin_amdgcn_s_barrier();
        __builtin_amdgcn_s_setprio(1);
#pragma unroll
        for (int ks = 0; ks < 4; ++ks) {
            acc[2][1] = MFMA32(bf1[ks], afHi[0][ks], acc[2][1]);
            acc[3][1] = MFMA32(bf1[ks], afHi[1][ks], acc[3][1]);
        }
        __builtin_amdgcn_s_setprio(0);
        __builtin_amdgcn_s_barrier();
    }
#undef STAGE_A
#undef STAGE_B

    // D^T layout: m-row = frag-row(l32), n-col = (r&3)+8*(r>>2)+4*hi
    unsigned short* outp = (n0 < 1024) ? Qb : Kb;
    const int cb = (n0 < 1024) ? n0 : n0 - 1024;
    const float QS = (n0 < 1024) ? 0.125f * 1.44269504f : 1.0f;
#pragma unroll
    for (int rf = 0; rf < 4; ++rf) {
        const int row = m0 + wr * 128 + rf * 32 + l32;
#pragma unroll
        for (int cf = 0; cf < 2; ++cf)
#pragma unroll
            for (int g = 0; g < 4; ++g) {
                const int col = cb + wc * 64 + cf * 32 + g * 8 + 4 * hi;
                uint2 v;
                v.x = pack2(acc[rf][cf][4 * g + 0] * QS, acc[rf][cf][4 * g + 1] * QS);
                v.y = pack2(acc[rf][cf][4 * g + 2] * QS, acc[rf][cf][4 * g + 3] * QS);
                *(uint2*)(outp + (size_t)row * 1024 + col) = v;
            }
    }
}

// ---------------------------------------------------------------- V GEMM
// 128x256 tile, BK=64, 8 waves (2Mx4N), 96KB LDS, 4-phase counted-vmcnt(5).
// Grid 64x4 = 256 blocks = exactly 1 round. Bt points at the V rows of wqkvT.
// Epilogue: sigma-permuted LDS-bounce transpose to Vt[bh][64 d][2048 t]
// (stored pos p in each 32-t block holds V[t=sigma(p)], sigma(8Q+e)=4Q+(e&3)+16*(e>=4)).
__global__ __launch_bounds__(512, 2) void gemm_v(const unsigned short* __restrict__ A,
                                                 const unsigned short* __restrict__ Bt,
                                                 unsigned short* __restrict__ Vt) {
    __shared__ __align__(16) unsigned short smem[49152]; // A[2][8192] | B[2][16384]

    const int tid  = threadIdx.x;
    const int wave = tid >> 6;
    const int lane = tid & 63;
    const int l32  = lane & 31;
    const int hi   = lane >> 5;
    const int wr   = wave >> 2;   // 0..1 (M)
    const int wc   = wave & 3;    // 0..3 (N) = head within block

    const int bid = blockIdx.x;
    const int sid = (bid & 7) * 32 + (bid >> 3);
    const int bx  = sid & 3;      // 4 N-blocks
    const int by  = sid >> 2;     // 64 M-blocks
    const int m0 = by * 128;
    const int n0 = bx * 256;

    const int srow = tid >> 3;
    const int cswz = (((tid & 7) ^ ((tid >> 3) & 7)) * 8);
    const unsigned short* gA = A  + (size_t)(m0 + srow) * 1024 + cswz;
    const unsigned short* gB = Bt + (size_t)(n0 + srow) * 1024 + cswz;

#define STAGE_A(buf, h, kt) do {                                              \
        const unsigned short* _g = gA + (size_t)((h) * 64) * 1024 + (kt) * 64; \
        unsigned short* _l = smem + (buf) * 8192 + (h) * 4096 + wave * 512;   \
        GLOAD16(_g, _l);                                                      \
    } while (0)
#define STAGE_B(buf, h, kt) do {                                              \
        const unsigned short* _g = gB + (size_t)((h) * 128) * 1024 + (kt) * 64; \
        unsigned short* _l = smem + 16384 + (buf) * 16384 + (h) * 8192 + wave * 512; \
        GLOAD16(_g, _l);                                                      \
        GLOAD16(_g + 65536, _l + 4096);                                       \
    } while (0)

    const int sw7  = l32 & 7;
    const int aoff = (wr * 64 + l32) * 64;
    const int boff = (wc * 64 + l32) * 64;

    f32x16 acc[2][2] = {};

    STAGE_A(0, 0, 0); STAGE_A(0, 1, 0); STAGE_B(0, 0, 0); STAGE_B(0, 1, 0);
    STAGE_B(1, 0, 1); STAGE_B(1, 1, 1); STAGE_A(1, 0, 1);
    asm volatile("s_waitcnt vmcnt(5)" ::: "memory");
    __builtin_amdgcn_s_barrier();

#pragma unroll
    for (int t = 0; t < 16; ++t) {
        const int b = t & 1;
        const unsigned short* Ab = smem + b * 8192;
        const unsigned short* Bb = smem + 16384 + b * 16384;

        short8 af0[4], af1[4], bf0[4], bf1[4];

        // -------- phase 1: af0 + bf0 | stage A1(t+1) | q0
#pragma unroll
        for (int ks = 0; ks < 4; ++ks)
            af0[ks] = *(const short8*)(Ab + aoff + (((ks * 2 + hi) ^ sw7) * 8));
#pragma unroll
        for (int ks = 0; ks < 4; ++ks)
            bf0[ks] = *(const short8*)(Bb + boff + (((ks * 2 + hi) ^ sw7) * 8));
        if (t + 1 < 16) STAGE_A(b ^ 1, 1, t + 1);
        __builtin_amdgcn_s_barrier();
        asm volatile("s_waitcnt lgkmcnt(0)" ::: "memory");
        __builtin_amdgcn_s_setprio(1);
#pragma unroll
        for (int ks = 0; ks < 4; ++ks)
            acc[0][0] = MFMA32(af0[ks], bf0[ks], acc[0][0]);
        __builtin_amdgcn_s_setprio(0);
        __builtin_amdgcn_s_barrier();

        // -------- phase 2: bf1 | q1
#pragma unroll
        for (int ks = 0; ks < 4; ++ks)
            bf1[ks] = *(const short8*)(Bb + boff + 2048 + (((ks * 2 + hi) ^ sw7) * 8));
        __builtin_amdgcn_s_barrier();
        asm volatile("s_waitcnt lgkmcnt(0)" ::: "memory");
        __builtin_amdgcn_s_setprio(1);
#pragma unroll
        for (int ks = 0; ks < 4; ++ks)
            acc[0][1] = MFMA32(af0[ks], bf1[ks], acc[0][1]);
        __builtin_amdgcn_s_setprio(0);
        __builtin_amdgcn_s_barrier();

        // -------- phase 3: af1 | stage B0,B1(t+2) | q2
#pragma unroll
        for (int ks = 0; ks < 4; ++ks)
            af1[ks] = *(const short8*)(Ab + aoff + 2048 + (((ks * 2 + hi) ^ sw7) * 8));
        if (t + 2 < 16) { STAGE_B(b, 0, t + 2); STAGE_B(b, 1, t + 2); }
        __builtin_amdgcn_s_barrier();
        asm volatile("s_waitcnt lgkmcnt(0)" ::: "memory");
        __builtin_amdgcn_s_setprio(1);
#pragma unroll
        for (int ks = 0; ks < 4; ++ks)
            acc[1][0] = MFMA32(af1[ks], bf0[ks], acc[1][0]);
        __builtin_amdgcn_s_setprio(0);
        __builtin_amdgcn_s_barrier();

        // -------- phase 4: stage A0(t+2) | counted vmcnt | q3
        if (t + 2 < 16) {
            STAGE_A(b, 0, t + 2);
            asm volatile("s_waitcnt vmcnt(5)" ::: "memory");
        } else {
            asm volatile("s_waitcnt vmcnt(0)" ::: "memory");
        }
        __builtin_amdgcn_s_barrier();
        __builtin_amdgcn_s_setprio(1);
#pragma unroll
        for (int ks = 0; ks < 4; ++ks)
            acc[1][1] = MFMA32(af1[ks], bf1[ks], acc[1][1]);
        __builtin_amdgcn_s_setprio(0);
        __builtin_amdgcn_s_barrier();
    }
#undef STAGE_A
#undef STAGE_B

    // bounce: [t][d] -> Vt[bh][d][t] with sigma order. 4 head-regions x 16KB.
    const int bb = m0 >> 11, t0b = m0 & 2047;
    const int hbase = n0 >> 6;           // 4 heads per block
    unsigned short* reg = smem + wc * 8192;
#pragma unroll
    for (int rf = 0; rf < 2; ++rf)
#pragma unroll
        for (int cf = 0; cf < 2; ++cf)
#pragma unroll
            for (int rg = 0; rg < 4; ++rg) {
                const int tl = wr * 64 + rf * 32 + rg * 8 + 4 * hi;
                const int d  = cf * 32 + l32;
                const int w  = d * 64 + ((tl >> 1) ^ (4 * (d & 7)));
                uint2 v;
                v.x = pack2(acc[rf][cf][4 * rg + 0], acc[rf][cf][4 * rg + 1]);
                v.y = pack2(acc[rf][cf][4 * rg + 2], acc[rf][cf][4 * rg + 3]);
                *(uint2*)(reg + 2 * w) = v;
            }
    __syncthreads();
    // 4 heads x 64 d x 16 t-octets = 4096 short8 stores / 512 threads
#pragma unroll
    for (int it = 0; it < 8; ++it) {
        const int id = it * 512 + tid;
        const int hh = id >> 10, d = (id >> 4) & 63, k = id & 15;
        const int kb = k >> 2, kl = k & 3;
        const int xx = 4 * (d & 7);
        const unsigned short* bp = smem + hh * 8192 + 2 * (d * 64);
        uint2 lo  = *(const uint2*)(bp + 2 * ((16 * kb + 2 * kl) ^ xx));
        uint2 hi2 = *(const uint2*)(bp + 2 * ((16 * kb + 2 * kl + 8) ^ xx));
        uint2 parts[2] = {lo, hi2};
        short8 v; __builtin_memcpy(&v, parts, 16);
        *(short8*)(Vt + ((size_t)((bb * 16 + hbase + hh) * 64 + d)) * 2048 + t0b + k * 8) = v;
    }
}

// ---------------------------------------------------------------- out-proj GEMM
// 128x256 tile, BK=64, 8 waves (2Mx4N), double-buffered 96KB LDS, 4-phase
// counted-vmcnt(5) schedule (per-wave 64x64, acc[2][2]).
__global__ __launch_bounds__(512, 2) void gemm_out(const unsigned short* __restrict__ A,
                                                   const unsigned short* __restrict__ Bt,
                                                   float* __restrict__ C) {
    __shared__ __align__(16) unsigned short smem[49152]; // A[2][8192] | B[2][16384]

    const int tid  = threadIdx.x;
    const int wave = tid >> 6;
    const int lane = tid & 63;
    const int l32  = lane & 31;
    const int hi   = lane >> 5;
    const int wr   = wave >> 2;   // 0..1 (M)
    const int wc   = wave & 3;    // 0..3 (N)

    const int bid = blockIdx.x;
    const int sid = (bid & 7) * 32 + (bid >> 3);
    const int bx  = sid & 3;      // 4 N-blocks
    const int by  = sid >> 2;     // 64 M-blocks
    const int m0 = by * 128;
    const int n0 = bx * 256;

    const int srow = tid >> 3;
    const int cswz = (((tid & 7) ^ ((tid >> 3) & 7)) * 8);
    const unsigned short* gA = A  + (size_t)(m0 + srow) * 1024 + cswz;
    const unsigned short* gB = Bt + (size_t)(n0 + srow) * 1024 + cswz;

#define STAGE_A(buf, h, kt) do {                                              \
        const unsigned short* _g = gA + (size_t)((h) * 64) * 1024 + (kt) * 64; \
        unsigned short* _l = smem + (buf) * 8192 + (h) * 4096 + wave * 512;   \
        GLOAD16(_g, _l);                                                      \
    } while (0)
#define STAGE_B(buf, h, kt) do {                                              \
        const unsigned short* _g = gB + (size_t)((h) * 128) * 1024 + (kt) * 64; \
        unsigned short* _l = smem + 16384 + (buf) * 16384 + (h) * 8192 + wave * 512; \
        GLOAD16(_g, _l);                                                      \
        GLOAD16(_g + 65536, _l + 4096);                                       \
    } while (0)

    const int sw7  = l32 & 7;
    const int aoff = (wr * 64 + l32) * 64;
    const int boff = (wc * 64 + l32) * 64;

    f32x16 acc[2][2] = {};

    STAGE_A(0, 0, 0); STAGE_A(0, 1, 0); STAGE_B(0, 0, 0); STAGE_B(0, 1, 0);
    STAGE_B(1, 0, 1); STAGE_B(1, 1, 1); STAGE_A(1, 0, 1);
    asm volatile("s_waitcnt vmcnt(5)" ::: "memory");
    __builtin_amdgcn_s_barrier();

#pragma unroll
    for (int t = 0; t < 16; ++t) {
        const int b = t & 1;
        const unsigned short* Ab = smem + b * 8192;
        const unsigned short* Bb = smem + 16384 + b * 16384;

        short8 af0[4], af1[4], bf0[4], bf1[4];

        // -------- phase 1: af0 + bf0 | stage A1(t+1) | q0
#pragma unroll
        for (int ks = 0; ks < 4; ++ks)
            af0[ks] = *(const short8*)(Ab + aoff + (((ks * 2 + hi) ^ sw7) * 8));
#pragma unroll
        for (int ks = 0; ks < 4; ++ks)
            bf0[ks] = *(const short8*)(Bb + boff + (((ks * 2 + hi) ^ sw7) * 8));
        if (t + 1 < 16) STAGE_A(b ^ 1, 1, t + 1);
        __builtin_amdgcn_s_barrier();
        asm volatile("s_waitcnt lgkmcnt(0)" ::: "memory");
        __builtin_amdgcn_s_setprio(1);
#pragma unroll
        for (int ks = 0; ks < 4; ++ks)
            acc[0][0] = MFMA32(af0[ks], bf0[ks], acc[0][0]);
        __builtin_amdgcn_s_setprio(0);
        __builtin_amdgcn_s_barrier();

        // -------- phase 2: bf1 | q1
#pragma unroll
        for (int ks = 0; ks < 4; ++ks)
            bf1[ks] = *(const short8*)(Bb + boff + 2048 + (((ks * 2 + hi) ^ sw7) * 8));
        __builtin_amdgcn_s_barrier();
        asm volatile("s_waitcnt lgkmcnt(0)" ::: "memory");
        __builtin_amdgcn_s_setprio(1);
#pragma unroll
        for (int ks = 0; ks < 4; ++ks)
            acc[0][1] = MFMA32(af0[ks], bf1[ks], acc[0][1]);
        __builtin_amdgcn_s_setprio(0);
        __builtin_amdgcn_s_barrier();

        // -------- phase 3: af1 | stage B0,B1(t+2) | q2
#pragma unroll
        for (int ks = 0; ks < 4; ++ks)
            af1[ks] = *(const short8*)(Ab + aoff + 2048 + (((ks * 2 + hi) ^ sw7) * 8));
        if (t + 2 < 16) { STAGE_B(b, 0, t + 2); STAGE_B(b, 1, t + 2); }
        __builtin_amdgcn_s_barrier();
        asm volatile("s_waitcnt lgkmcnt(0)" ::: "memory");
        __builtin_amdgcn_s_setprio(1);
#pragma unroll
        for (int ks = 0; ks < 4; ++ks)
            acc[1][0] = MFMA32(af1[ks], bf0[ks], acc[1][0]);
        __builtin_amdgcn_s_setprio(0);
        __builtin_amdgcn_s_barrier();

        // -------- phase 4: stage A0(t+2) | counted vmcnt | q3
        if (t + 2 < 16) {
            STAGE_A(b, 0, t + 2);
            asm volatile("s_waitcnt vmcnt(5)" ::: "memory");
        } else {
            asm volatile("s_waitcnt vmcnt(0)" ::: "memory");
        }
        __builtin_amdgcn_s_barrier();
        __builtin_amdgcn_s_setprio(1);
#pragma unroll
        for (int ks = 0; ks < 4; ++ks)
            acc[1][1] = MFMA32(af1[ks], bf1[ks], acc[1][1]);
        __builtin_amdgcn_s_setprio(0);
        __builtin_amdgcn_s_barrier();
    }
#undef STAGE_A
#undef STAGE_B

#pragma unroll
    for (int rf = 0; rf < 2; ++rf)
#pragma unroll
        for (int cf = 0; cf < 2; ++cf)
#pragma unroll
            for (int r = 0; r < 16; ++r) {
                int row = m0 + wr * 64 + rf * 32 + (r & 3) + 8 * (r >> 2) + 4 * hi;
                int col = n0 + wc * 64 + cf * 32 + l32;
                C[(size_t)row * 1024 + col] = acc[rf][cf][r];
            }
}

// ---------------------------------------------------------------- flash attention (S^T formulation)
// 512 uniform blocks x 256 threads (4 waves). Block = (pair p, head hb);
// pass0 = q-block 15-p, pass1 = q-block p -> exactly 17 KVBLK-128 iterations.
// Each wave owns 32 q-rows as two groups A (qb*128+w*16) and B (A+64): the same
// kf/vf LDS fragments feed both groups (2x K/V reuse, half the LDS read traffic).
// KVBLK=128 double-buffered 64KB LDS, counted vmcnt(8) prefetch, in-register
// sigma-P, MFMA-ones row-sum. Q pre-scaled.
__global__ __launch_bounds__(256, 2) void attention_kernel(const unsigned short* Qb,
                                                           const unsigned short* Kb,
                                                           const unsigned short* Vt,
                                                           unsigned short* attn) {
    const int T = 2048;
    const int bi = blockIdx.x;
    const int pp = bi >> 6;          // 0..7 pair index
    const int hb = bi & 63;
    const int b = hb >> 4, h = hb & 15;
    const int tid = threadIdx.x, wave = tid >> 6, lane = tid & 63;
    const int l16 = lane & 15, quad = lane >> 4;

    const unsigned short* Qp  = Qb + (size_t)b * T * 1024 + h * 64;
    const unsigned short* Kp  = Kb + (size_t)b * T * 1024 + h * 64;
    const unsigned short* Vbh = Vt + ((size_t)(b * 16 + h) * 64) * 2048;

    // dbuf x { sub0: K[2][64t][32d] + V[2][64d][32t] (8192 shorts) | sub1 }
    __shared__ __align__(16) unsigned short smem[2][16384];

    const f32x4 fz = {};
    short8 onesf;
#pragma unroll
    for (int e = 0; e < 8; e++) onesf[e] = (short)0x3F80;

    const int srow = lane >> 2;
    const int scol = (((lane & 3) ^ ((lane >> 3) & 3)) * 8);
    const int sw8  = ((l16 >> 1) & 3) * 8;

    // staging: waves 0-1 -> K (panel = wave), 2-3 -> V (th = wave-2);
    // each wave issues 4 GLOAD16 per 64-t tile (rows r: chunk r>>4).
    const unsigned short* gs0;
    size_t ktstep, rstep;
    int lofs;
    if (wave < 2) {
        gs0 = Kp + (size_t)srow * 1024 + wave * 32 + scol;
        ktstep = (size_t)64 * 1024; rstep = 1024;
        lofs = wave * 2048;
    } else {
        const int th = wave - 2;
        gs0 = Vbh + (size_t)srow * 2048 + th * 32 + scol;
        ktstep = (size_t)64; rstep = 2048;
        lofs = 4096 + th * 2048;
    }

#define STAGE(bb, k64, sub) do {                                  \
        const unsigned short* _g = gs0 + (size_t)(k64) * ktstep;  \
        unsigned short* _l = &smem[bb][0] + (sub) * 8192 + lofs;  \
        GLOAD16(_g,              _l);                             \
        GLOAD16(_g + 16 * rstep, _l + 512);                       \
        GLOAD16(_g + 32 * rstep, _l + 1024);                      \
        GLOAD16(_g + 48 * rstep, _l + 1536);                      \
    } while (0)

    for (int pass = 0; pass < 2; ++pass) {
        const int qb = pass ? pp : (15 - pp);   // long pass first
        const int qw0A = qb * 128 + wave * 16;
        const int qw0B = qw0A + 64;

        short8 qfA[2], qfB[2];
#pragma unroll
        for (int kd = 0; kd < 2; kd++) {
            qfA[kd] = *(const short8*)(Qp + (size_t)(qw0A + l16) * 1024 + kd * 32 + quad * 8);
            qfB[kd] = *(const short8*)(Qp + (size_t)(qw0B + l16) * 1024 + kd * 32 + quad * 8);
        }
        asm volatile("" ::: "memory");

        f32x4 oA[4] = {}, oB[4] = {};
        f32x4 olA = {}, olB = {};

        STAGE(0, 0, 0); STAGE(0, 1, 1);
        const int last = qb;                    // KVBLK-128 tiles 0..qb
        for (int kt = 0; kt <= last; kt++) {
            const int bsel = kt & 1;
            if (kt < last) {
                STAGE(bsel ^ 1, 2 * (kt + 1), 0);
                STAGE(bsel ^ 1, 2 * (kt + 1) + 1, 1);
                asm volatile("s_waitcnt vmcnt(8)" ::: "memory");
            } else {
                asm volatile("s_waitcnt vmcnt(0)" ::: "memory");
            }
            __builtin_amdgcn_s_barrier();
            asm volatile("" ::: "memory");

#pragma unroll
            for (int sub = 0; sub < 2; ++sub) {
                const int tk0 = kt * 128 + sub * 64;
                const unsigned short* Kb0 = &smem[bsel][sub * 8192];
                const unsigned short* Kb1 = Kb0 + 2048;
                const unsigned short* Vb0 = Kb0 + 4096;

#pragma unroll
                for (int th = 0; th < 2; th++) {
                    const int t0a = tk0 + th * 32;
                    if (t0a > qw0B + 15) continue;
                    const int t1 = t0a + 16;
                    const bool actA  = (t0a <= qw0A + 15);
                    const bool act1B = (t1 <= qw0B + 15);
                    const bool act1A = (t1 <= qw0A + 15);

                    // shared K frag reads; QK^T for both q-groups
                    f32x4 s0A, s0B, s1A, s1B;
                    {
                        const int row = (th * 2) * 16 + l16;
                        short8 kf0 = *(const short8*)(Kb0 + row * 32 + (quad * 8 ^ sw8));
                        short8 kf1 = *(const short8*)(Kb1 + row * 32 + (quad * 8 ^ sw8));
                        s0B = MFMA16(kf0, qfB[0], fz);
                        s0B = MFMA16(kf1, qfB[1], s0B);
                        if (actA) {
                            s0A = MFMA16(kf0, qfA[0], fz);
                            s0A = MFMA16(kf1, qfA[1], s0A);
                        }
                    }
                    if (act1B) {
                        const int row = (th * 2 + 1) * 16 + l16;
                        short8 kf0 = *(const short8*)(Kb0 + row * 32 + (quad * 8 ^ sw8));
                        short8 kf1 = *(const short8*)(Kb1 + row * 32 + (quad * 8 ^ sw8));
                        s1B = MFMA16(kf0, qfB[0], fz);
                        s1B = MFMA16(kf1, qfB[1], s1B);
                        if (act1A) {
                            s1A = MFMA16(kf0, qfA[0], fz);
                            s1A = MFMA16(kf1, qfA[1], s1A);
                        }
                    }

                    // softmax numerators, packed in-register (sigma order)
                    unsigned uB0, uB1, uB2, uB3;
                    {
                        const bool full = (t0a + 15) <= qw0B;
                        float p[4];
#pragma unroll
                        for (int r = 0; r < 4; r++) {
                            float e = __builtin_amdgcn_exp2f(s0B[r]);
                            if (!full)
                                e = (t0a + quad * 4 + r <= qw0B + l16) ? e : 0.f;
                            p[r] = e;
                        }
                        uB0 = pack2(p[0], p[1]);
                        uB1 = pack2(p[2], p[3]);
                    }
                    if (act1B) {
                        const bool full = (t1 + 15) <= qw0B;
                        float p[4];
#pragma unroll
                        for (int r = 0; r < 4; r++) {
                            float e = __builtin_amdgcn_exp2f(s1B[r]);
                            if (!full)
                                e = (t1 + quad * 4 + r <= qw0B + l16) ? e : 0.f;
                            p[r] = e;
                        }
                        uB2 = pack2(p[0], p[1]);
                        uB3 = pack2(p[2], p[3]);
                    } else {
                        uB2 = 0; uB3 = 0;
                    }
                    unsigned uA0 = 0, uA1 = 0, uA2 = 0, uA3 = 0;
                    if (actA) {
                        const bool full = (t0a + 15) <= qw0A;
                        float p[4];
#pragma unroll
                        for (int r = 0; r < 4; r++) {
                            float e = __builtin_amdgcn_exp2f(s0A[r]);
                            if (!full)
                                e = (t0a + quad * 4 + r <= qw0A + l16) ? e : 0.f;
                            p[r] = e;
                        }
                        uA0 = pack2(p[0], p[1]);
                        uA1 = pack2(p[2], p[3]);
                        if (act1A) {
                            const bool fullH = (t1 + 15) <= qw0A;
                            float q[4];
#pragma unroll
                            for (int r = 0; r < 4; r++) {
                                float e = __builtin_amdgcn_exp2f(s1A[r]);
                                if (!fullH)
                                    e = (t1 + quad * 4 + r <= qw0A + l16) ? e : 0.f;
                                q[r] = e;
                            }
                            uA2 = pack2(q[0], q[1]);
                            uA3 = pack2(q[2], q[3]);
                        }
                    }

                    unsigned pbB[4] = {uB0, uB1, uB2, uB3};
                    short8 pfB; __builtin_memcpy(&pfB, pbB, 16);
                    unsigned pbA[4] = {uA0, uA1, uA2, uA3};
                    short8 pfA; __builtin_memcpy(&pfA, pbA, 16);

                    __builtin_amdgcn_s_setprio(1);
                    olB = MFMA16(onesf, pfB, olB);
                    if (actA) olA = MFMA16(onesf, pfA, olA);
#pragma unroll
                    for (int dt = 0; dt < 4; dt++) {
                        short8 vf = *(const short8*)(Vb0 + th * 2048 + (dt * 16 + l16) * 32 + (quad * 8 ^ sw8));
                        oB[dt] = MFMA16(vf, pfB, oB[dt]);
                        if (actA) oA[dt] = MFMA16(vf, pfA, oA[dt]);
                    }
                    __builtin_amdgcn_s_setprio(0);
                }
            }
            asm volatile("" ::: "memory");
            __builtin_amdgcn_s_barrier();
        }

        // epilogue: both q-groups
        {
            const float rlA = 1.f / olA[0];
            const float rlB = 1.f / olB[0];
            const int qA = qw0A + l16;
            const int qB = qw0B + l16;
#pragma unroll
            for (int dt = 0; dt < 4; dt++) {
                ushort4 wv;
                wv.x = f2b(oA[dt][0] * rlA);
                wv.y = f2b(oA[dt][1] * rlA);
                wv.z = f2b(oA[dt][2] * rlA);
                wv.w = f2b(oA[dt][3] * rlA);
                *(ushort4*)(attn + (size_t)(b * T + qA) * 1024 + h * 64 + dt * 16 + quad * 4) = wv;
                ushort4 wv2;
                wv2.x = f2b(oB[dt][0] * rlB);
                wv2.y = f2b(oB[dt][1] * rlB);
                wv2.z = f2b(oB[dt][2] * rlB);
                wv2.w = f2b(oB[dt][3] * rlB);
                *(ushort4*)(attn + (size_t)(b * T + qB) * 1024 + h * 64 + dt * 16 + quad * 4) = wv2;
            }
        }
    }
#undef STAGE
}

// ---------------------------------------------------------------- launch
extern "C" void kernel_launch(void* const* d_in, const int* in_sizes, int n_in,
                              void* d_out, int out_size, void* d_ws, size_t ws_size,
                              hipStream_t stream) {
    const float* x     = (const float*)d_in[0]; // (4,2048,1024)
    const float* w_qkv = (const float*)d_in[1]; // (1024,3072)
    const float* w_out = (const float*)d_in[2]; // (1024,1024)
    float* out = (float*)d_out;

    const int M = 8192, D = 1024, E = 3072;
    const size_t MB = 1048576;

    char* ws = (char*)d_ws;
    unsigned short* xb    = (unsigned short*)ws;              // 16 MB
    unsigned short* wqkvT = (unsigned short*)(ws + 16 * MB);  // 6 MB
    unsigned short* woutT = (unsigned short*)(ws + 22 * MB);  // 2 MB
    unsigned short* Qb    = (unsigned short*)(ws + 24 * MB);  // 16 MB (reused as attn out)
    unsigned short* Kb    = (unsigned short*)(ws + 40 * MB);  // 16 MB
    unsigned short* Vt    = (unsigned short*)(ws + 56 * MB);  // 16 MB -> 72 MB total

    cast4_kernel<<<M * D / 4 / 256, 256, 0, stream>>>(x, xb, M * D / 4);
    transpose_cast_f32<<<dim3(E / 64, D / 64), 256, 0, stream>>>(w_qkv, wqkvT, D, E);
    transpose_cast_f32<<<dim3(D / 64, D / 64), 256, 0, stream>>>(w_out, woutT, D, D);

    // Q/K: 256x256 tiles, 32x8 = 256 blocks (1 exact round)
    gemm_qk<<<dim3(256), 512, 0, stream>>>(xb, wqkvT, Qb, Kb);
    // V: 128x256 tiles, 64x4 = 256 blocks (1 exact round)
    gemm_v<<<dim3(256), 512, 0, stream>>>(xb, wqkvT + (size_t)2048 * 1024, Vt);

    // 512 uniform paired blocks (8 pairs x 64 bh), 256 threads, 64KB LDS
    attention_kernel<<<dim3(512), 256, 0, stream>>>(Qb, Kb, Vt, Qb);

    // 128x256 tiles: 64*4 = 256 blocks, 512 threads
    gemm_out<<<dim3(256), 512, 0, stream>>>(Qb, woutT, out);
}

// Round 7
// 239.972 us; speedup vs baseline: 1.1241x; 1.1241x over previous
//
#include <hip/hip_runtime.h>
#include <hip/hip_bf16.h>

typedef short short8 __attribute__((ext_vector_type(8)));
typedef float f32x4 __attribute__((ext_vector_type(4)));
typedef float f32x16 __attribute__((ext_vector_type(16)));

#define MFMA16(a, b, c) __builtin_amdgcn_mfma_f32_16x16x32_bf16((a), (b), (c), 0, 0, 0)
#define MFMA32(a, b, c) __builtin_amdgcn_mfma_f32_32x32x16_bf16((a), (b), (c), 0, 0, 0)

// async global->LDS, 16B per lane; LDS dest = wave-uniform base + lane*16
#define GLOAD16(gp, lp)                                                    \
    __builtin_amdgcn_global_load_lds(                                      \
        (const __attribute__((address_space(1))) unsigned int*)(gp),       \
        (__attribute__((address_space(3))) unsigned int*)(lp), 16, 0, 0)

__device__ __forceinline__ unsigned short f2b(float x) {
    unsigned int u = __float_as_uint(x);
    unsigned int r = u + 0x7FFFu + ((u >> 16) & 1u);
    return (unsigned short)(r >> 16);
}

#if __has_builtin(__builtin_amdgcn_cvt_pk_bf16_f32)
__device__ __forceinline__ unsigned pack2(float a, float b) {
    auto v = __builtin_amdgcn_cvt_pk_bf16_f32(a, b);
    unsigned u;
    __builtin_memcpy(&u, &v, 4);
    return u;
}
#else
__device__ __forceinline__ unsigned pack2(float a, float b) {
    return (unsigned)f2b(a) | ((unsigned)f2b(b) << 16);
}
#endif

// ---------------------------------------------------------------- fused preprocessing
// blocks [0,8192): x -> bf16 cast. [8192,8960): w_qkv transpose. [8960,9216): w_out.
__device__ __forceinline__ void transpose_body(const float* __restrict__ in,
                                               unsigned short* __restrict__ out,
                                               int K, int N, int k0, int n0,
                                               unsigned short* Ls, int tid) {
    const int krow = tid >> 4, nc4 = (tid & 15) * 4;
#pragma unroll
    for (int p = 0; p < 4; p++) {
        float4 v = *(const float4*)(in + (size_t)(k0 + krow + p * 16) * N + n0 + nc4);
        unsigned* d32 = (unsigned*)(Ls + (krow + p * 16) * 66 + nc4);
        d32[0] = pack2(v.x, v.y);
        d32[1] = pack2(v.z, v.w);
    }
    __syncthreads();
    const int n = tid >> 3, kc = (tid & 7) * 8;
#pragma unroll
    for (int p = 0; p < 2; p++) {
        int nn = n + p * 32;
        unsigned short w[8];
#pragma unroll
        for (int j = 0; j < 8; j++) w[j] = Ls[(kc + j) * 66 + nn];
        *(short8*)(out + (size_t)(n0 + nn) * K + k0 + kc) = *(short8*)w;
    }
}

__global__ __launch_bounds__(256) void prep_kernel(const float* __restrict__ x,
                                                   unsigned short* __restrict__ xb,
                                                   const float* __restrict__ w_qkv,
                                                   unsigned short* __restrict__ wqkvT,
                                                   const float* __restrict__ w_out,
                                                   unsigned short* __restrict__ woutT) {
    __shared__ unsigned short Ls[64 * 66];
    const int bid = blockIdx.x, tid = threadIdx.x;
    if (bid < 8192) {
        int i = bid * 256 + tid;   // n4 = 8192*256 exactly
        float4 v = ((const float4*)x)[i];
        ushort4 o;
        o.x = f2b(v.x); o.y = f2b(v.y); o.z = f2b(v.z); o.w = f2b(v.w);
        ((ushort4*)xb)[i] = o;
    } else if (bid < 8960) {
        const int b2 = bid - 8192;          // 768 blocks: N=3072 (48) x K=1024 (16)
        transpose_body(w_qkv, wqkvT, 1024, 3072, (b2 / 48) * 64, (b2 % 48) * 64, Ls, tid);
    } else {
        const int b3 = bid - 8960;          // 256 blocks: 16 x 16
        transpose_body(w_out, woutT, 1024, 1024, (b3 >> 4) * 64, (b3 & 15) * 64, Ls, tid);
    }
}

// ---------------------------------------------------------------- fused QKV GEMM
// blocks [0,256): Q/K path — 256x256 tile, BK=64, 128KB LDS, 4-phase vmcnt(6),
//   swapped MFMA (D^T) -> packed 8B stores. 1 block/CU, exactly 1 round.
// blocks [256,512): V path — 128x256 tile, 96KB LDS, 4-phase vmcnt(5),
//   sigma-permuted LDS-bounce transpose to Vt[bh][64 d][2048 t].
__global__ __launch_bounds__(512, 2) void gemm_qkv(const unsigned short* __restrict__ A,
                                                   const unsigned short* __restrict__ BtQK,
                                                   const unsigned short* __restrict__ BtV,
                                                   unsigned short* __restrict__ Qb,
                                                   unsigned short* __restrict__ Kb,
                                                   unsigned short* __restrict__ Vt) {
    __shared__ __align__(16) unsigned short smem[65536]; // 128KB, V path uses first 96KB

    const int tid  = threadIdx.x;
    const int wave = tid >> 6;
    const int lane = tid & 63;
    const int l32  = lane & 31;
    const int hi   = lane >> 5;
    const int wr   = wave >> 2;
    const int wc   = wave & 3;
    const int sw7  = l32 & 7;
    const int srow = tid >> 3;
    const int cswz = (((tid & 7) ^ ((tid >> 3) & 7)) * 8);

    if (blockIdx.x < 256) {
        // ---------------- Q/K path ----------------
        const int bid = blockIdx.x;
        const int sid = (bid & 7) * 32 + (bid >> 3);
        const int bx  = sid & 7;
        const int by  = sid >> 3;
        const int m0 = by * 256;
        const int n0 = bx * 256;

        const unsigned short* gA = A    + (size_t)(m0 + srow) * 1024 + cswz;
        const unsigned short* gB = BtQK + (size_t)(n0 + srow) * 1024 + cswz;

#define STAGE_A(buf, h, kt) do {                                              \
        const unsigned short* _g = gA + (size_t)((h) * 128) * 1024 + (kt) * 64; \
        unsigned short* _l = smem + (buf) * 16384 + (h) * 8192 + wave * 512;  \
        GLOAD16(_g, _l);                                                      \
        GLOAD16(_g + 65536, _l + 4096);                                       \
    } while (0)
#define STAGE_B(buf, h, kt) do {                                              \
        const unsigned short* _g = gB + (size_t)((h) * 128) * 1024 + (kt) * 64; \
        unsigned short* _l = smem + 32768 + (buf) * 16384 + (h) * 8192 + wave * 512; \
        GLOAD16(_g, _l);                                                      \
        GLOAD16(_g + 65536, _l + 4096);                                       \
    } while (0)

        const int aoff = (wr * 128 + l32) * 64;
        const int boff = (wc * 64 + l32) * 64;

        f32x16 acc[4][2] = {};

        STAGE_A(0, 0, 0); STAGE_A(0, 1, 0); STAGE_B(0, 0, 0); STAGE_B(0, 1, 0);
        STAGE_B(1, 0, 1); STAGE_B(1, 1, 1); STAGE_A(1, 0, 1);
        asm volatile("s_waitcnt vmcnt(6)" ::: "memory");
        __builtin_amdgcn_s_barrier();

#pragma unroll
        for (int t = 0; t < 16; ++t) {
            const int b = t & 1;
            const unsigned short* Ab = smem + b * 16384;
            const unsigned short* Bb = smem + 32768 + b * 16384;

            short8 afLo[2][4], afHi[2][4], bf0[4], bf1[4];

            // phase 1: afLo + bf0 | stage A1(t+1) | q0
#pragma unroll
            for (int rf = 0; rf < 2; ++rf)
#pragma unroll
                for (int ks = 0; ks < 4; ++ks)
                    afLo[rf][ks] = *(const short8*)(Ab + aoff + rf * 2048 + (((ks * 2 + hi) ^ sw7) * 8));
#pragma unroll
            for (int ks = 0; ks < 4; ++ks)
                bf0[ks] = *(const short8*)(Bb + boff + (((ks * 2 + hi) ^ sw7) * 8));
            if (t + 1 < 16) STAGE_A(b ^ 1, 1, t + 1);
            __builtin_amdgcn_s_barrier();
            asm volatile("s_waitcnt lgkmcnt(0)" ::: "memory");
            __builtin_amdgcn_s_setprio(1);
#pragma unroll
            for (int ks = 0; ks < 4; ++ks) {
                acc[0][0] = MFMA32(bf0[ks], afLo[0][ks], acc[0][0]);
                acc[1][0] = MFMA32(bf0[ks], afLo[1][ks], acc[1][0]);
            }
            __builtin_amdgcn_s_setprio(0);
            __builtin_amdgcn_s_barrier();

            // phase 2: bf1 | q1
#pragma unroll
            for (int ks = 0; ks < 4; ++ks)
                bf1[ks] = *(const short8*)(Bb + boff + 2048 + (((ks * 2 + hi) ^ sw7) * 8));
            __builtin_amdgcn_s_barrier();
            asm volatile("s_waitcnt lgkmcnt(0)" ::: "memory");
            __builtin_amdgcn_s_setprio(1);
#pragma unroll
            for (int ks = 0; ks < 4; ++ks) {
                acc[0][1] = MFMA32(bf1[ks], afLo[0][ks], acc[0][1]);
                acc[1][1] = MFMA32(bf1[ks], afLo[1][ks], acc[1][1]);
            }
            __builtin_amdgcn_s_setprio(0);
            __builtin_amdgcn_s_barrier();

            // phase 3: afHi | stage B0,B1(t+2) | q2
#pragma unroll
            for (int rf = 0; rf < 2; ++rf)
#pragma unroll
                for (int ks = 0; ks < 4; ++ks)
                    afHi[rf][ks] = *(const short8*)(Ab + aoff + (2 + rf) * 2048 + (((ks * 2 + hi) ^ sw7) * 8));
            if (t + 2 < 16) { STAGE_B(b, 0, t + 2); STAGE_B(b, 1, t + 2); }
            __builtin_amdgcn_s_barrier();
            asm volatile("s_waitcnt lgkmcnt(0)" ::: "memory");
            __builtin_amdgcn_s_setprio(1);
#pragma unroll
            for (int ks = 0; ks < 4; ++ks) {
                acc[2][0] = MFMA32(bf0[ks], afHi[0][ks], acc[2][0]);
                acc[3][0] = MFMA32(bf0[ks], afHi[1][ks], acc[3][0]);
            }
            __builtin_amdgcn_s_setprio(0);
            __builtin_amdgcn_s_barrier();

            // phase 4: stage A0(t+2) | counted vmcnt | q3
            if (t + 2 < 16) {
                STAGE_A(b, 0, t + 2);
                asm volatile("s_waitcnt vmcnt(6)" ::: "memory");
            } else {
                asm volatile("s_waitcnt vmcnt(0)" ::: "memory");
            }
            __builtin_amdgcn_s_barrier();
            __builtin_amdgcn_s_setprio(1);
#pragma unroll
            for (int ks = 0; ks < 4; ++ks) {
                acc[2][1] = MFMA32(bf1[ks], afHi[0][ks], acc[2][1]);
                acc[3][1] = MFMA32(bf1[ks], afHi[1][ks], acc[3][1]);
            }
            __builtin_amdgcn_s_setprio(0);
            __builtin_amdgcn_s_barrier();
        }
#undef STAGE_A
#undef STAGE_B

        // D^T layout: m-row = frag-row(l32), n-col = (r&3)+8*(r>>2)+4*hi
        unsigned short* outp = (n0 < 1024) ? Qb : Kb;
        const int cb = (n0 < 1024) ? n0 : n0 - 1024;
        const float QS = (n0 < 1024) ? 0.125f * 1.44269504f : 1.0f;
#pragma unroll
        for (int rf = 0; rf < 4; ++rf) {
            const int row = m0 + wr * 128 + rf * 32 + l32;
#pragma unroll
            for (int cf = 0; cf < 2; ++cf)
#pragma unroll
                for (int g = 0; g < 4; ++g) {
                    const int col = cb + wc * 64 + cf * 32 + g * 8 + 4 * hi;
                    uint2 v;
                    v.x = pack2(acc[rf][cf][4 * g + 0] * QS, acc[rf][cf][4 * g + 1] * QS);
                    v.y = pack2(acc[rf][cf][4 * g + 2] * QS, acc[rf][cf][4 * g + 3] * QS);
                    *(uint2*)(outp + (size_t)row * 1024 + col) = v;
                }
        }
    } else {
        // ---------------- V path ----------------
        const int bid = blockIdx.x - 256;
        const int sid = (bid & 7) * 32 + (bid >> 3);
        const int bx  = sid & 3;
        const int by  = sid >> 2;
        const int m0 = by * 128;
        const int n0 = bx * 256;

        const unsigned short* gA = A   + (size_t)(m0 + srow) * 1024 + cswz;
        const unsigned short* gB = BtV + (size_t)(n0 + srow) * 1024 + cswz;

#define STAGE_A(buf, h, kt) do {                                              \
        const unsigned short* _g = gA + (size_t)((h) * 64) * 1024 + (kt) * 64; \
        unsigned short* _l = smem + (buf) * 8192 + (h) * 4096 + wave * 512;   \
        GLOAD16(_g, _l);                                                      \
    } while (0)
#define STAGE_B(buf, h, kt) do {                                              \
        const unsigned short* _g = gB + (size_t)((h) * 128) * 1024 + (kt) * 64; \
        unsigned short* _l = smem + 16384 + (buf) * 16384 + (h) * 8192 + wave * 512; \
        GLOAD16(_g, _l);                                                      \
        GLOAD16(_g + 65536, _l + 4096);                                       \
    } while (0)

        const int aoff = (wr * 64 + l32) * 64;
        const int boff = (wc * 64 + l32) * 64;

        f32x16 acc[2][2] = {};

        STAGE_A(0, 0, 0); STAGE_A(0, 1, 0); STAGE_B(0, 0, 0); STAGE_B(0, 1, 0);
        STAGE_B(1, 0, 1); STAGE_B(1, 1, 1); STAGE_A(1, 0, 1);
        asm volatile("s_waitcnt vmcnt(5)" ::: "memory");
        __builtin_amdgcn_s_barrier();

#pragma unroll
        for (int t = 0; t < 16; ++t) {
            const int b = t & 1;
            const unsigned short* Ab = smem + b * 8192;
            const unsigned short* Bb = smem + 16384 + b * 16384;

            short8 af0[4], af1[4], bf0[4], bf1[4];

            // phase 1: af0 + bf0 | stage A1(t+1) | q0
#pragma unroll
            for (int ks = 0; ks < 4; ++ks)
                af0[ks] = *(const short8*)(Ab + aoff + (((ks * 2 + hi) ^ sw7) * 8));
#pragma unroll
            for (int ks = 0; ks < 4; ++ks)
                bf0[ks] = *(const short8*)(Bb + boff + (((ks * 2 + hi) ^ sw7) * 8));
            if (t + 1 < 16) STAGE_A(b ^ 1, 1, t + 1);
            __builtin_amdgcn_s_barrier();
            asm volatile("s_waitcnt lgkmcnt(0)" ::: "memory");
            __builtin_amdgcn_s_setprio(1);
#pragma unroll
            for (int ks = 0; ks < 4; ++ks)
                acc[0][0] = MFMA32(af0[ks], bf0[ks], acc[0][0]);
            __builtin_amdgcn_s_setprio(0);
            __builtin_amdgcn_s_barrier();

            // phase 2: bf1 | q1
#pragma unroll
            for (int ks = 0; ks < 4; ++ks)
                bf1[ks] = *(const short8*)(Bb + boff + 2048 + (((ks * 2 + hi) ^ sw7) * 8));
            __builtin_amdgcn_s_barrier();
            asm volatile("s_waitcnt lgkmcnt(0)" ::: "memory");
            __builtin_amdgcn_s_setprio(1);
#pragma unroll
            for (int ks = 0; ks < 4; ++ks)
                acc[0][1] = MFMA32(af0[ks], bf1[ks], acc[0][1]);
            __builtin_amdgcn_s_setprio(0);
            __builtin_amdgcn_s_barrier();

            // phase 3: af1 | stage B0,B1(t+2) | q2
#pragma unroll
            for (int ks = 0; ks < 4; ++ks)
                af1[ks] = *(const short8*)(Ab + aoff + 2048 + (((ks * 2 + hi) ^ sw7) * 8));
            if (t + 2 < 16) { STAGE_B(b, 0, t + 2); STAGE_B(b, 1, t + 2); }
            __builtin_amdgcn_s_barrier();
            asm volatile("s_waitcnt lgkmcnt(0)" ::: "memory");
            __builtin_amdgcn_s_setprio(1);
#pragma unroll
            for (int ks = 0; ks < 4; ++ks)
                acc[1][0] = MFMA32(af1[ks], bf0[ks], acc[1][0]);
            __builtin_amdgcn_s_setprio(0);
            __builtin_amdgcn_s_barrier();

            // phase 4: stage A0(t+2) | counted vmcnt | q3
            if (t + 2 < 16) {
                STAGE_A(b, 0, t + 2);
                asm volatile("s_waitcnt vmcnt(5)" ::: "memory");
            } else {
                asm volatile("s_waitcnt vmcnt(0)" ::: "memory");
            }
            __builtin_amdgcn_s_barrier();
            __builtin_amdgcn_s_setprio(1);
#pragma unroll
            for (int ks = 0; ks < 4; ++ks)
                acc[1][1] = MFMA32(af1[ks], bf1[ks], acc[1][1]);
            __builtin_amdgcn_s_setprio(0);
            __builtin_amdgcn_s_barrier();
        }
#undef STAGE_A
#undef STAGE_B

        // bounce: [t][d] -> Vt[bh][d][t] with sigma order (sigma(8Q+e)=4Q+(e&3)+16*(e>=4))
        const int bb = m0 >> 11, t0b = m0 & 2047;
        const int hbase = n0 >> 6;
        unsigned short* reg = smem + wc * 8192;
#pragma unroll
        for (int rf = 0; rf < 2; ++rf)
#pragma unroll
            for (int cf = 0; cf < 2; ++cf)
#pragma unroll
                for (int rg = 0; rg < 4; ++rg) {
                    const int tl = wr * 64 + rf * 32 + rg * 8 + 4 * hi;
                    const int d  = cf * 32 + l32;
                    const int w  = d * 64 + ((tl >> 1) ^ (4 * (d & 7)));
                    uint2 v;
                    v.x = pack2(acc[rf][cf][4 * rg + 0], acc[rf][cf][4 * rg + 1]);
                    v.y = pack2(acc[rf][cf][4 * rg + 2], acc[rf][cf][4 * rg + 3]);
                    *(uint2*)(reg + 2 * w) = v;
                }
        __syncthreads();
#pragma unroll
        for (int it = 0; it < 8; ++it) {
            const int id = it * 512 + tid;
            const int hh = id >> 10, d = (id >> 4) & 63, k = id & 15;
            const int kb = k >> 2, kl = k & 3;
            const int xx = 4 * (d & 7);
            const unsigned short* bp = smem + hh * 8192 + 2 * (d * 64);
            uint2 lo  = *(const uint2*)(bp + 2 * ((16 * kb + 2 * kl) ^ xx));
            uint2 hi2 = *(const uint2*)(bp + 2 * ((16 * kb + 2 * kl + 8) ^ xx));
            uint2 parts[2] = {lo, hi2};
            short8 v; __builtin_memcpy(&v, parts, 16);
            *(short8*)(Vt + ((size_t)((bb * 16 + hbase + hh) * 64 + d)) * 2048 + t0b + k * 8) = v;
        }
    }
}

// ---------------------------------------------------------------- out-proj GEMM
// 128x256 tile, BK=64, 8 waves (2Mx4N), double-buffered 96KB LDS, 4-phase
// counted-vmcnt(5) schedule (per-wave 64x64, acc[2][2]).
__global__ __launch_bounds__(512, 2) void gemm_out(const unsigned short* __restrict__ A,
                                                   const unsigned short* __restrict__ Bt,
                                                   float* __restrict__ C) {
    __shared__ __align__(16) unsigned short smem[49152]; // A[2][8192] | B[2][16384]

    const int tid  = threadIdx.x;
    const int wave = tid >> 6;
    const int lane = tid & 63;
    const int l32  = lane & 31;
    const int hi   = lane >> 5;
    const int wr   = wave >> 2;   // 0..1 (M)
    const int wc   = wave & 3;    // 0..3 (N)

    const int bid = blockIdx.x;
    const int sid = (bid & 7) * 32 + (bid >> 3);
    const int bx  = sid & 3;      // 4 N-blocks
    const int by  = sid >> 2;     // 64 M-blocks
    const int m0 = by * 128;
    const int n0 = bx * 256;

    const int srow = tid >> 3;
    const int cswz = (((tid & 7) ^ ((tid >> 3) & 7)) * 8);
    const unsigned short* gA = A  + (size_t)(m0 + srow) * 1024 + cswz;
    const unsigned short* gB = Bt + (size_t)(n0 + srow) * 1024 + cswz;

#define STAGE_A(buf, h, kt) do {                                              \
        const unsigned short* _g = gA + (size_t)((h) * 64) * 1024 + (kt) * 64; \
        unsigned short* _l = smem + (buf) * 8192 + (h) * 4096 + wave * 512;   \
        GLOAD16(_g, _l);                                                      \
    } while (0)
#define STAGE_B(buf, h, kt) do {                                              \
        const unsigned short* _g = gB + (size_t)((h) * 128) * 1024 + (kt) * 64; \
        unsigned short* _l = smem + 16384 + (buf) * 16384 + (h) * 8192 + wave * 512; \
        GLOAD16(_g, _l);                                                      \
        GLOAD16(_g + 65536, _l + 4096);                                       \
    } while (0)

    const int sw7  = l32 & 7;
    const int aoff = (wr * 64 + l32) * 64;
    const int boff = (wc * 64 + l32) * 64;

    f32x16 acc[2][2] = {};

    STAGE_A(0, 0, 0); STAGE_A(0, 1, 0); STAGE_B(0, 0, 0); STAGE_B(0, 1, 0);
    STAGE_B(1, 0, 1); STAGE_B(1, 1, 1); STAGE_A(1, 0, 1);
    asm volatile("s_waitcnt vmcnt(5)" ::: "memory");
    __builtin_amdgcn_s_barrier();

#pragma unroll
    for (int t = 0; t < 16; ++t) {
        const int b = t & 1;
        const unsigned short* Ab = smem + b * 8192;
        const unsigned short* Bb = smem + 16384 + b * 16384;

        short8 af0[4], af1[4], bf0[4], bf1[4];

        // phase 1: af0 + bf0 | stage A1(t+1) | q0
#pragma unroll
        for (int ks = 0; ks < 4; ++ks)
            af0[ks] = *(const short8*)(Ab + aoff + (((ks * 2 + hi) ^ sw7) * 8));
#pragma unroll
        for (int ks = 0; ks < 4; ++ks)
            bf0[ks] = *(const short8*)(Bb + boff + (((ks * 2 + hi) ^ sw7) * 8));
        if (t + 1 < 16) STAGE_A(b ^ 1, 1, t + 1);
        __builtin_amdgcn_s_barrier();
        asm volatile("s_waitcnt lgkmcnt(0)" ::: "memory");
        __builtin_amdgcn_s_setprio(1);
#pragma unroll
        for (int ks = 0; ks < 4; ++ks)
            acc[0][0] = MFMA32(af0[ks], bf0[ks], acc[0][0]);
        __builtin_amdgcn_s_setprio(0);
        __builtin_amdgcn_s_barrier();

        // phase 2: bf1 | q1
#pragma unroll
        for (int ks = 0; ks < 4; ++ks)
            bf1[ks] = *(const short8*)(Bb + boff + 2048 + (((ks * 2 + hi) ^ sw7) * 8));
        __builtin_amdgcn_s_barrier();
        asm volatile("s_waitcnt lgkmcnt(0)" ::: "memory");
        __builtin_amdgcn_s_setprio(1);
#pragma unroll
        for (int ks = 0; ks < 4; ++ks)
            acc[0][1] = MFMA32(af0[ks], bf1[ks], acc[0][1]);
        __builtin_amdgcn_s_setprio(0);
        __builtin_amdgcn_s_barrier();

        // phase 3: af1 | stage B0,B1(t+2) | q2
#pragma unroll
        for (int ks = 0; ks < 4; ++ks)
            af1[ks] = *(const short8*)(Ab + aoff + 2048 + (((ks * 2 + hi) ^ sw7) * 8));
        if (t + 2 < 16) { STAGE_B(b, 0, t + 2); STAGE_B(b, 1, t + 2); }
        __builtin_amdgcn_s_barrier();
        asm volatile("s_waitcnt lgkmcnt(0)" ::: "memory");
        __builtin_amdgcn_s_setprio(1);
#pragma unroll
        for (int ks = 0; ks < 4; ++ks)
            acc[1][0] = MFMA32(af1[ks], bf0[ks], acc[1][0]);
        __builtin_amdgcn_s_setprio(0);
        __builtin_amdgcn_s_barrier();

        // phase 4: stage A0(t+2) | counted vmcnt | q3
        if (t + 2 < 16) {
            STAGE_A(b, 0, t + 2);
            asm volatile("s_waitcnt vmcnt(5)" ::: "memory");
        } else {
            asm volatile("s_waitcnt vmcnt(0)" ::: "memory");
        }
        __builtin_amdgcn_s_barrier();
        __builtin_amdgcn_s_setprio(1);
#pragma unroll
        for (int ks = 0; ks < 4; ++ks)
            acc[1][1] = MFMA32(af1[ks], bf1[ks], acc[1][1]);
        __builtin_amdgcn_s_setprio(0);
        __builtin_amdgcn_s_barrier();
    }
#undef STAGE_A
#undef STAGE_B

#pragma unroll
    for (int rf = 0; rf < 2; ++rf)
#pragma unroll
        for (int cf = 0; cf < 2; ++cf)
#pragma unroll
            for (int r = 0; r < 16; ++r) {
                int row = m0 + wr * 64 + rf * 32 + (r & 3) + 8 * (r >> 2) + 4 * hi;
                int col = n0 + wc * 64 + cf * 32 + l32;
                C[(size_t)row * 1024 + col] = acc[rf][cf][r];
            }
}

// ---------------------------------------------------------------- flash attention (S^T formulation)
// R5 configuration (verified 68.5us): 512 UNIFORM blocks x 512 threads;
// block = (pair p, head hb); pass0 = q-block 15-p, pass1 = q-block p
// -> every block runs exactly 17 K-tile iterations (perfect causal balance).
// KVBLK=128 (two 64-t sub-tiles per barrier epoch), double-buffered 64KB LDS,
// counted vmcnt(4) prefetch. In-register sigma-P, MFMA-ones row-sum. Q pre-scaled.
__global__ __launch_bounds__(512, 4) void attention_kernel(const unsigned short* Qb,
                                                           const unsigned short* Kb,
                                                           const unsigned short* Vt,
                                                           unsigned short* attn) {
    const int T = 2048;
    const int bi = blockIdx.x;
    const int pp = bi >> 6;          // 0..7 pair index
    const int hb = bi & 63;
    const int b = hb >> 4, h = hb & 15;
    const int tid = threadIdx.x, wave = tid >> 6, lane = tid & 63;
    const int l16 = lane & 15, quad = lane >> 4;

    const unsigned short* Qp  = Qb + (size_t)b * T * 1024 + h * 64;
    const unsigned short* Kp  = Kb + (size_t)b * T * 1024 + h * 64;
    const unsigned short* Vbh = Vt + ((size_t)(b * 16 + h) * 64) * 2048;

    // dbuf x { sub0: K[2][64t][32d] + V[2][64d][32t] (8192) | sub1: 8192 }
    __shared__ __align__(16) unsigned short smem[2][16384];

    const f32x4 fz = {};
    short8 onesf;
#pragma unroll
    for (int e = 0; e < 8; e++) onesf[e] = (short)0x3F80;

    const int srow = lane >> 2;
    const int scol = (((lane & 3) ^ ((lane >> 3) & 3)) * 8);
    const int sw8  = ((l16 >> 1) & 3) * 8;

    // staging assignment: waves 0-3 -> K (panel=d-half, chunk-pair), 4-7 -> V
    const unsigned short* gs;
    size_t ktstep, jstep;
    int lofs;
    if (wave < 4) {
        const int p = wave >> 1, cp = wave & 1;
        gs = Kp + (size_t)(cp * 32 + srow) * 1024 + p * 32 + scol;
        ktstep = (size_t)64 * 1024; jstep = (size_t)16 * 1024;
        lofs = p * 2048 + cp * 1024;
    } else {
        const int u = wave - 4, th = u >> 1, cp = u & 1;
        gs = Vbh + (size_t)(cp * 32 + srow) * 2048 + th * 32 + scol;
        ktstep = (size_t)64; jstep = (size_t)16 * 2048;
        lofs = 4096 + th * 2048 + cp * 1024;
    }

// k64 = global 64-t tile index; sub = which half of the 128-t buffer
#define STAGE(bb, k64, sub) do {                               \
        const unsigned short* _g = gs + (size_t)(k64) * ktstep; \
        unsigned short* _l = &smem[bb][0] + (sub) * 8192 + lofs; \
        GLOAD16(_g, _l);                                        \
        GLOAD16(_g + jstep, _l + 512);                          \
    } while (0)

    for (int pass = 0; pass < 2; ++pass) {
        const int qb = pass ? pp : (15 - pp);   // long pass first
        const int qw0 = qb * 128 + wave * 16;

        short8 qf[2];
#pragma unroll
        for (int kd = 0; kd < 2; kd++)
            qf[kd] = *(const short8*)(Qp + (size_t)(qw0 + l16) * 1024 + kd * 32 + quad * 8);
        asm volatile("" ::: "memory");

        f32x4 o[4] = {};
        f32x4 o_l = {};

        STAGE(0, 0, 0); STAGE(0, 1, 1);
        const int last = qb;                    // 128-t tiles 0..qb
        for (int kt = 0; kt <= last; kt++) {
            const int bsel = kt & 1;
            if (kt < last) {
                STAGE(bsel ^ 1, 2 * (kt + 1), 0);
                STAGE(bsel ^ 1, 2 * (kt + 1) + 1, 1);
                asm volatile("s_waitcnt vmcnt(4)" ::: "memory");
            } else {
                asm volatile("s_waitcnt vmcnt(0)" ::: "memory");
            }
            __builtin_amdgcn_s_barrier();
            asm volatile("" ::: "memory");

#pragma unroll
            for (int sub = 0; sub < 2; ++sub) {
                const int tk0 = kt * 128 + sub * 64;
                const unsigned short* Kb0 = &smem[bsel][sub * 8192];
                const unsigned short* Kb1 = Kb0 + 2048;
                const unsigned short* Vb0 = Kb0 + 4096;

#pragma unroll
                for (int th = 0; th < 2; th++) {
                    const int t0a = tk0 + th * 32;
                    if (t0a > qw0 + 15) continue;
                    const int t1 = t0a + 16;
                    const bool act1 = (t1 <= qw0 + 15);

                    // QK^T (S^T tiles): lane holds q=l16, k=quad*4+r
                    f32x4 s0, s1;
                    {
                        const int row = (th * 2) * 16 + l16;
                        short8 kf0 = *(const short8*)(Kb0 + row * 32 + (quad * 8 ^ sw8));
                        short8 kf1 = *(const short8*)(Kb1 + row * 32 + (quad * 8 ^ sw8));
                        s0 = MFMA16(kf0, qf[0], fz);
                        s0 = MFMA16(kf1, qf[1], s0);
                    }
                    if (act1) {
                        const int row = (th * 2 + 1) * 16 + l16;
                        short8 kf0 = *(const short8*)(Kb0 + row * 32 + (quad * 8 ^ sw8));
                        short8 kf1 = *(const short8*)(Kb1 + row * 32 + (quad * 8 ^ sw8));
                        s1 = MFMA16(kf0, qf[0], fz);
                        s1 = MFMA16(kf1, qf[1], s1);
                    }

                    // softmax numerator, packed in-register
                    unsigned u00, u01, u10, u11;
                    {
                        const bool full = (t0a + 15) <= qw0;
                        float p[4];
#pragma unroll
                        for (int r = 0; r < 4; r++) {
                            float e = __builtin_amdgcn_exp2f(s0[r]);
                            if (!full)
                                e = (t0a + quad * 4 + r <= qw0 + l16) ? e : 0.f;
                            p[r] = e;
                        }
                        u00 = pack2(p[0], p[1]);
                        u01 = pack2(p[2], p[3]);
                    }
                    if (act1) {
                        const bool full = (t1 + 15) <= qw0;
                        float p[4];
#pragma unroll
                        for (int r = 0; r < 4; r++) {
                            float e = __builtin_amdgcn_exp2f(s1[r]);
                            if (!full)
                                e = (t1 + quad * 4 + r <= qw0 + l16) ? e : 0.f;
                            p[r] = e;
                        }
                        u10 = pack2(p[0], p[1]);
                        u11 = pack2(p[2], p[3]);
                    } else {
                        u10 = 0; u11 = 0;
                    }

                    // B-fragment: element e of lane-group Q covers t = sigma(8Q+e);
                    // Vt stores matching sigma order, so no redistribution needed.
                    unsigned pb[4] = {u00, u01, u10, u11};
                    short8 pf; __builtin_memcpy(&pf, pb, 16);

                    __builtin_amdgcn_s_setprio(1);
                    o_l = MFMA16(onesf, pf, o_l);
#pragma unroll
                    for (int dt = 0; dt < 4; dt++) {
                        short8 vf = *(const short8*)(Vb0 + th * 2048 + (dt * 16 + l16) * 32 + (quad * 8 ^ sw8));
                        o[dt] = MFMA16(vf, pf, o[dt]);
                    }
                    __builtin_amdgcn_s_setprio(0);
                }
            }
            asm volatile("" ::: "memory");
            __builtin_amdgcn_s_barrier();
        }

        const float rl = 1.f / o_l[0];
        const int q = qw0 + l16;
#pragma unroll
        for (int dt = 0; dt < 4; dt++) {
            ushort4 wv;
            wv.x = f2b(o[dt][0] * rl);
            wv.y = f2b(o[dt][1] * rl);
            wv.z = f2b(o[dt][2] * rl);
            wv.w = f2b(o[dt][3] * rl);
            *(ushort4*)(attn + (size_t)(b * T + q) * 1024 + h * 64 + dt * 16 + quad * 4) = wv;
        }
    }
#undef STAGE
}

// ---------------------------------------------------------------- launch
extern "C" void kernel_launch(void* const* d_in, const int* in_sizes, int n_in,
                              void* d_out, int out_size, void* d_ws, size_t ws_size,
                              hipStream_t stream) {
    const float* x     = (const float*)d_in[0]; // (4,2048,1024)
    const float* w_qkv = (const float*)d_in[1]; // (1024,3072)
    const float* w_out = (const float*)d_in[2]; // (1024,1024)
    float* out = (float*)d_out;

    const size_t MB = 1048576;

    char* ws = (char*)d_ws;
    unsigned short* xb    = (unsigned short*)ws;              // 16 MB
    unsigned short* wqkvT = (unsigned short*)(ws + 16 * MB);  // 6 MB
    unsigned short* woutT = (unsigned short*)(ws + 22 * MB);  // 2 MB
    unsigned short* Qb    = (unsigned short*)(ws + 24 * MB);  // 16 MB (reused as attn out)
    unsigned short* Kb    = (unsigned short*)(ws + 40 * MB);  // 16 MB
    unsigned short* Vt    = (unsigned short*)(ws + 56 * MB);  // 16 MB -> 72 MB total

    // fused preprocessing: 8192 cast blocks + 768 + 256 transpose blocks
    prep_kernel<<<dim3(9216), 256, 0, stream>>>(x, xb, w_qkv, wqkvT, w_out, woutT);

    // fused QKV: [0,256) Q/K (256^2 tiles), [256,512) V (128x256 tiles)
    gemm_qkv<<<dim3(512), 512, 0, stream>>>(xb, wqkvT, wqkvT + (size_t)2048 * 1024,
                                            Qb, Kb, Vt);

    // 512 uniform paired blocks (8 pairs x 64 bh), 512 threads, 64KB LDS
    attention_kernel<<<dim3(512), 512, 0, stream>>>(Qb, Kb, Vt, Qb);

    // 128x256 tiles: 64*4 = 256 blocks, 512 threads
    gemm_out<<<dim3(256), 512, 0, stream>>>(Qb, woutT, out);
}